// Round 9
// baseline (120.470 us; speedup 1.0000x reference)
//
#include <hip/hip_runtime.h>

// Quantizer_189: 1-D VQ codebook lookup. x: [16,1,512,512] fp32 (N=4,194,304
// scalars; C=D=1 so transposes are no-ops), weight: [128,1].
//
// Reference model (NumPy fp32, per-op rounding, NO fma — verified rounds 3-8,
// absmax == 0.0):
//   dist_k = fl( fl( fl(x*x) + fl(w_k*w_k) ) - fl( fl(2x) * w_k ) )
//   idx    = np.argmin(dist) — first ORIGINAL index wins ties
//   out    = w[idx]
//
// Round-9: round 8's VGPR=24 showed the compiler serialized the divergent
// LDS reads (1 outstanding/wave -> latency-bound, 48 us). Changes:
//  - batch-4 phase-structured hot loop: 4 spak reads in flight, then per
//    window level 4 svrep reads in flight + 4 independent eval chains.
//    __launch_bounds__(256,8) allows up to 64 VGPR at full 8 waves/SIMD.
//  - LDS 20.5KB -> 8.2KB: svrep8 = x8-replicated sorted values (4KB,
//    lane%8 copy -> ~2 lanes/bank avg), spak 4KB. Setup kernel now writes
//    only sv(128)+spak(1024) to d_ws; hot kernel builds svrep8 locally.
//
// CRITICAL (rounds 1/2/5 lessons): device -ffp-contract fuses mul into
// sub -> fma (breaks bit-exactness) — keep pragma + NON-volatile asm
// barriers on every product (volatile asm serializes).

constexpr int K     = 128;   // codebook capacity
constexpr int G     = 1024;  // cells
constexpr int EPT   = 8;     // elements per thread
constexpr int BLOCK = 256;
constexpr int W     = 10;    // hot window width  (covers span <= 2)
constexpr int WW    = 16;    // wide window width (covers span <= 8)

// d_ws layout (32-bit words):
//   [0] lo  [1] invW  [2] kk  [3] mode          (16 B header)
//   [4 .. 4+K)        sv   (sorted codebook, 512 B, 16B-aligned)
//   [4+K .. 4+K+G)    spak (packed cell records, 4 KB, 16B-aligned)
constexpr int WS_WORDS = 4 + K + G;

__device__ __forceinline__ int cellOf(float v, float lo, float invW) {
#pragma clang fp contract(off)
    float tf = (v - lo) * invW;   // monotone fp map (identical in both kernels)
    int c = (int)tf;
    return c < 0 ? 0 : (c > G - 1 ? G - 1 : c);
}

__global__ __launch_bounds__(BLOCK) void setup_kernel(const float* __restrict__ w,
                                                      float* __restrict__ ws,
                                                      int kk) {
#pragma clang fp contract(off)
    __shared__ float wl[K];
    __shared__ float sv[K];
    __shared__ int   cnt[G + 1];
    const int t = threadIdx.x;
    const float INF = __builtin_inff();

    if (t < K) { wl[t] = (t < kk) ? w[t] : INF; sv[t] = INF; }
    __syncthreads();
    if (t < kk) {
        // Stable O(K) rank sort (wl[j] uniform -> broadcast reads).
        float v = wl[t];
        int rank = 0;
        for (int j = 0; j < kk; ++j) {
            float u = wl[j];
            rank += (u < v) || (u == v && j < t);
        }
        sv[rank] = v;
    }
    __syncthreads();

    const float lo   = sv[0];
    const float hi   = sv[kk - 1];
    const float invW = (hi > lo) ? ((float)G / (hi - lo)) : 0.0f;

    if (t < kk) {
        // cnt[c] = #{entries with cell < c}, via interval writes.
        int cj = cellOf(sv[t], lo, invW);
        int cp = (t == 0) ? -1 : cellOf(sv[t - 1], lo, invW);
        for (int c = cp + 1; c <= cj; ++c) cnt[c] = t;
        if (t == kk - 1)
            for (int c = cj + 1; c <= G; ++c) cnt[c] = kk;
    }
    __syncthreads();

    if (t == 0) {
        ws[0] = lo;
        ws[1] = invW;
        ((int*)ws)[2] = kk;
        ((int*)ws)[3] = (kk >= WW) ? 0 : 1;   // mode 1: brute everything
    }
    if (t < K) ws[4 + t] = sv[t];
    unsigned* spak = (unsigned*)(ws + 4 + K);
    int smaxH = kk - W;  if (smaxH < 0) smaxH = 0;
    for (int c = t; c < G; c += BLOCK) {
        int c0 = cnt[c], c1 = cnt[c + 1];
        int s = c0 - 4;  s = s < 0 ? 0 : (s > smaxH ? smaxH : s);
        unsigned wide = (c1 - c0 > W - 8) ? 0x80000000u : 0u;
        spak[c] = (unsigned)s | ((unsigned)c0 << 8) | ((unsigned)c1 << 16) | wide;
    }
}

__device__ __forceinline__ float bruteOne(float xv, const float* __restrict__ w,
                                          int kk) {
#pragma clang fp contract(off)
    // Exact brute force in ORIGINAL order (np.argmin first-index via strict <).
    float x2 = xv * xv;  asm("" : "+v"(x2));
    float tx = xv + xv;
    float best = __builtin_inff(), bwv = 0.0f;
    for (int k = 0; k < kk; ++k) {
        float wv = w[k];                       // uniform -> broadcast, L2-hot
        float w2 = wv * wv;  asm("" : "+v"(w2));
        float sum  = x2 + w2;
        float prod = tx * wv; asm("" : "+v"(prod));
        float d = sum - prod;
        if (d < best) { best = d; bwv = wv; }
    }
    return bwv;
}

__global__ __launch_bounds__(BLOCK, 8) void vq_kernel(const float* __restrict__ x,
                                                      const float* __restrict__ w,
                                                      float* __restrict__ out,
                                                      const float* __restrict__ ws,
                                                      long n) {
#pragma clang fp contract(off)
    __shared__ float    svrep8[K * 8];  // 4 KB: x8-replicated sorted values
    __shared__ unsigned spak[G];        // 4 KB: packed cell records

    const int t = threadIdx.x;
    const int r = t & 7;                // replication slot
    const float INF = __builtin_inff();

    // Stage: spak via one float4/thread; svrep8 built from sv (t<128).
    ((float4*)spak)[t] = ((const float4*)(ws + 4 + K))[t];
    if (t < K) {
        float v = ws[4 + t];
        float4 vv = make_float4(v, v, v, v);
        ((float4*)svrep8)[t * 2]     = vv;
        ((float4*)svrep8)[t * 2 + 1] = vv;
    }
    const float lo   = ws[0];
    const float invW = ws[1];
    const int   kk   = ((const int*)ws)[2];
    const int   mode = ((const int*)ws)[3];
    __syncthreads();

    long base = ((long)blockIdx.x * BLOCK + t) * (long)EPT;
    if (mode == 0 && base + EPT <= n) {
        float4 a = *(const float4*)(x + base);
        float4 b = *(const float4*)(x + base + 4);
        float xs[EPT] = {a.x, a.y, a.z, a.w, b.x, b.y, b.z, b.w};
        float res[EPT];
        int slowBits = 0;

#pragma unroll
        for (int bb = 0; bb < EPT / 4; ++bb) {
            // ---- phase 1: 4 hashes + 4 spak reads in flight ----
            unsigned pk[4];
#pragma unroll
            for (int e = 0; e < 4; ++e)
                pk[e] = spak[cellOf(xs[bb * 4 + e], lo, invW)];
            // ---- phase 2: bases + per-element state ----
            int wb[4];
            float x2[4], tx[4], best[4], bw[4];
            bool tie[4];
#pragma unroll
            for (int e = 0; e < 4; ++e) {
                float xv = xs[bb * 4 + e];
                float xx = xv * xv;  asm("" : "+v"(xx));  // fl(x*x), no fusion
                x2[e] = xx;
                tx[e] = xv + xv;                          // fl(2x), exact
                wb[e] = (((int)(pk[e] & 0xffu)) << 3) | r;
                best[e] = INF; bw[e] = 0.0f; tie[e] = false;
            }
            // ---- phase 3: 10 window levels, 4 reads + 4 evals per level ----
#pragma unroll
            for (int cc = 0; cc < W; ++cc) {
                float wv[4];
#pragma unroll
                for (int e = 0; e < 4; ++e)
                    wv[e] = svrep8[wb[e] + (cc << 3)];
#pragma unroll
                for (int e = 0; e < 4; ++e) {
                    float w2 = wv[e] * wv[e];  asm("" : "+v"(w2));   // fl(w*w)
                    float sum  = x2[e] + w2;                         // fl(x^2+w^2)
                    float prod = tx[e] * wv[e]; asm("" : "+v"(prod));// fl(2x*w)
                    float d = sum - prod;                            // fl(sum-prod)
                    bool lt = d < best[e];
                    bool eq = (!lt) && (d == best[e]);
                    tie[e]  = lt ? false : (tie[e] || eq);
                    best[e] = lt ? d      : best[e];
                    bw[e]   = lt ? wv[e]  : bw[e];
                }
            }
#pragma unroll
            for (int e = 0; e < 4; ++e) {
                res[bb * 4 + e] = bw[e];
                slowBits |= (tie[e] || (int)pk[e] < 0) ? (1 << (bb * 4 + e)) : 0;
            }
        }

        // Cold: wide window (span<=8) or escalate to brute.
        if (__builtin_expect(__any(slowBits != 0), 0)) {
            int smaxW = kk - WW;  if (smaxW < 0) smaxW = 0;
            for (int e = 0; e < EPT; ++e) {
                if (!(slowBits & (1 << e))) continue;
                float xv = xs[e];
                float xx = xv * xv;  asm("" : "+v"(xx));
                float txv = xv + xv;
                int c = cellOf(xv, lo, invW);
                unsigned pk = spak[c];
                int c0 = (int)((pk >> 8)  & 0xffu);
                int c1 = (int)((pk >> 16) & 0xffu);
                int s  = c0 - 4;  s = s < 0 ? 0 : (s > smaxW ? smaxW : s);
                float best = INF, bwv = 0.0f;
                bool tie = false;
                for (int cc = 0; cc < WW; ++cc) {
                    float wv = svrep8[((s + cc) << 3) | r];
                    float w2 = wv * wv;  asm("" : "+v"(w2));
                    float sum  = xx + w2;
                    float prod = txv * wv; asm("" : "+v"(prod));
                    float d = sum - prod;
                    bool lt = d < best;
                    bool eq = (!lt) && (d == best);
                    tie  = lt ? false : (tie || eq);
                    best = lt ? d  : best;
                    bwv  = lt ? wv : bwv;
                }
                res[e] = (tie || (c1 - c0 > WW - 8)) ? bruteOne(xv, w, kk) : bwv;
            }
        }

        *(float4*)(out + base)     = make_float4(res[0], res[1], res[2], res[3]);
        *(float4*)(out + base + 4) = make_float4(res[4], res[5], res[6], res[7]);
    } else {
        // Tail or tiny-codebook mode: exact brute force per scalar.
        long end = base + EPT; if (end > n) end = n;
        for (long i = base; i < end; ++i) out[i] = bruteOne(x[i], w, kk);
    }
}

// Fallback if d_ws is too small for the tables (not expected): plain brute.
__global__ __launch_bounds__(BLOCK) void vq_brute(const float* __restrict__ x,
                                                  const float* __restrict__ w,
                                                  float* __restrict__ out,
                                                  long n, int kk) {
#pragma clang fp contract(off)
    long base = ((long)blockIdx.x * BLOCK + threadIdx.x) * (long)EPT;
    long end = base + EPT; if (end > n) end = n;
    for (long i = base; i < end; ++i) out[i] = bruteOne(x[i], w, kk);
}

extern "C" void kernel_launch(void* const* d_in, const int* in_sizes, int n_in,
                              void* d_out, int out_size, void* d_ws, size_t ws_size,
                              hipStream_t stream) {
    const float* x = (const float*)d_in[0];
    const float* w = (const float*)d_in[1];
    float* out     = (float*)d_out;
    long n  = (long)in_sizes[0];
    int  kk = in_sizes[1] < K ? in_sizes[1] : K;

    long perBlock = (long)BLOCK * EPT;
    long grid = (n + perBlock - 1) / perBlock;

    if (ws_size < sizeof(float) * WS_WORDS) {
        vq_brute<<<(int)grid, BLOCK, 0, stream>>>(x, w, out, n, kk);
        return;
    }
    float* ws = (float*)d_ws;
    setup_kernel<<<1, BLOCK, 0, stream>>>(w, ws, kk);
    vq_kernel<<<(int)grid, BLOCK, 0, stream>>>(x, w, out, ws, n);
}